// Round 4
// baseline (302.989 us; speedup 1.0000x reference)
//
#include <hip/hip_runtime.h>

// Problem constants (from reference)
#define B_ 2048
#define S_ 200
#define D_ 128
#define H_ 64
#define KB_ 8                  // batches per persistent block
#define GRID_ (B_ / KB_)       // 256 blocks = 1 per CU (LDS-forced)
#define MASK_SCALE 1e10f

typedef __attribute__((ext_vector_type(8))) short short8_t;            // 8 bf16 in 4 VGPRs
typedef __attribute__((ext_vector_type(4))) float f32x4;
typedef __attribute__((ext_vector_type(4))) unsigned short ushort4_t;  // 8B

__device__ __forceinline__ unsigned short f2bf(float f) {
    unsigned u = __float_as_uint(f);
    unsigned r = (u + 0x7fffu + ((u >> 16) & 1u)) >> 16;   // round-to-nearest-even
    return (unsigned short)r;
}
__device__ __forceinline__ float bf2f(unsigned short v) {
    return __uint_as_float(((unsigned)v) << 16);
}
// packed f32x2 -> bf16x2, RNE, 1 instruction
__device__ __forceinline__ unsigned cvt_pk_bf16(float lo, float hi) {
    unsigned r;
    asm("v_cvt_pk_bf16_f32 %0, %1, %2" : "=v"(r) : "v"(lo), "v"(hi));
    return r;
}
// Barrier that does NOT drain vmcnt: lets prefetch loads stay in flight.
__device__ __forceinline__ void bar() {
    asm volatile("s_waitcnt lgkmcnt(0)\n\ts_barrier" ::: "memory");
}

// ---------------------------------------------------------------------------
// Persistent fused kernel, deep-pipelined: 256 blocks x 512 threads, 8
// batches each, double-buffered his tile (2 x 51.2 KB, XOR-swizzled bf16).
//
// Pipeline (the change this round): batch n+2's loads are issued at the END
// of iteration n, immediately after the conversion phase frees the x regs --
// BEFORE bar D / out-write / th-reads -- so HBM has zero idle window across
// iteration boundaries. The prologue likewise issues batch 1 before batch
// 0's conversion and uses raw (non-vmcnt-draining) barriers throughout, so
// the stream never drains. tproj partials ping-pong (tpp[2][]) because the
// hoisted tproj-write would otherwise WAR the same-iteration th-read.
// ---------------------------------------------------------------------------
__global__ __launch_bounds__(512, 2) void fused_kernel(const float* __restrict__ his,
                                                       const float* __restrict__ mask,
                                                       const float* __restrict__ target,
                                                       const float* __restrict__ W,
                                                       const float* __restrict__ W_bias,
                                                       const float* __restrict__ Ovec,
                                                       float* __restrict__ out) {
    __shared__ unsigned short hisb[2][S_ * D_];     // 2 x 51,200 B, swizzled
    __shared__ float alph[208];                     // raw alpha (13 tiles x 16)
    __shared__ float attw[208];                     // exp(a - m), unnormalized
    __shared__ float red8[8];                       // per-wave max
    __shared__ float red8b[8];                      // per-wave expsum
    __shared__ float ov_s[H_];
    __shared__ float tpp[2][8 * H_];                // tproj partials, ping-pong
    __shared__ float pool_s[7 * D_];                // pooling cross-wave partials

    const int t    = threadIdx.x;
    const int lane = t & 63;
    const int wv   = t >> 6;       // 0..7
    const int lm   = lane & 15;
    const int q    = lane >> 4;
    const int b0   = blockIdx.x * KB_;

    if (t < H_) ov_s[t] = Ovec[t];
    const float wb = (wv == 0) ? W_bias[lane] : 0.f;

    short8_t bfrag[16];            // persistent MFMA B fragments (64 VGPR)
    float4 wsl[4];                 // persistent (W3-W2)^T[h=lane][d=wv*16..+15]
    float4 x[13];                  // in-flight his batch (fp32)
    float4 tg[4];                  // in-flight target
    float mk, mkn;

    // ================= prologue =================
    {
        // (1) W first (earliest consumer: staging at ~200 cyc)
        const float4* W4 = (const float4*)W;
        float4 w1v[4], w2v[4], w3v[4];
        #pragma unroll
        for (int k = 0; k < 4; ++k) {
            int j = t + k * 512;
            w1v[k] = W4[j];
            w2v[k] = W4[j + 2048];
            w3v[k] = W4[j + 4096];
        }
        // (2) batch-0 his stream
        const float4* hb4 = (const float4*)(his + (size_t)b0 * S_ * D_);
        float4 x0[13];
        #pragma unroll
        for (int j = 0; j < 13; ++j) {
            int i = t + j * 512;
            if (i < 6400) x0[j] = hb4[i];
        }
        float4 tg0[4];
        {
            const float4* tg4 = (const float4*)(target + (size_t)b0 * D_) + wv * 4;
            #pragma unroll
            for (int k = 0; k < 4; ++k) tg0[k] = tg4[k];
        }
        mk = (t < S_) ? mask[(size_t)b0 * S_ + t] : 0.f;
        // (3) batch-1 prefetch (tg/mask before bulk: earlier consumers)
        {
            const float4* tg4 = (const float4*)(target + (size_t)(b0 + 1) * D_) + wv * 4;
            #pragma unroll
            for (int k = 0; k < 4; ++k) tg[k] = tg4[k];
        }
        mkn = (t < S_) ? mask[(size_t)(b0 + 1) * S_ + t] : 0.f;
        {
            const float4* hb4n = (const float4*)(his + (size_t)(b0 + 1) * S_ * D_);
            #pragma unroll
            for (int j = 0; j < 13; ++j) {
                int i = t + j * 512;
                if (i < 6400) x[j] = hb4n[i];
            }
        }
        __builtin_amdgcn_sched_barrier(0);   // all prologue loads issued

        // (4) stage W-derived data into the (currently free) second his buffer
        unsigned short* wf_s = hisb[1];                      // 16 KB bf16, frag order
        float* wdt_s = (float*)((char*)hisb[1] + 16384);     // 32 KB f32 [h][128]
        #pragma unroll
        for (int k = 0; k < 4; ++k) {
            int j = t + k * 512;
            int e = 4 * j;
            int d = e >> 6;          // 0..127
            int h = e & 63;          // multiple of 4
            float whc[4] = { w1v[k].x + w2v[k].x, w1v[k].y + w2v[k].y,
                             w1v[k].z + w2v[k].z, w1v[k].w + w2v[k].w };
            float wdc[4] = { w3v[k].x - w2v[k].x, w3v[k].y - w2v[k].y,
                             w3v[k].z - w2v[k].z, w3v[k].w - w2v[k].w };
            int kt = d >> 5, qd = (d >> 3) & 3, jj = d & 7;
            #pragma unroll
            for (int c = 0; c < 4; ++c) {
                int hh = h + c;
                int nt = hh >> 4, lmh = hh & 15;
                int ln = (qd << 4) | lmh;
                wf_s[((kt * 4 + nt) * 64 + ln) * 8 + jj] = f2bf(whc[c]);
                wdt_s[hh * D_ + d] = wdc[c];
            }
        }
        bar();   // W staged visible; his streams stay in flight

        // (5) persistent registers from staged LDS
        #pragma unroll
        for (int f = 0; f < 16; ++f)
            bfrag[f] = *(const short8_t*)(wf_s + (size_t)(f * 64 + lane) * 8);
        #pragma unroll
        for (int k = 0; k < 4; ++k)
            wsl[k] = *(const float4*)(wdt_s + lane * D_ + wv * 16 + k * 4);

        // (6) batch-0 tproj partial -> tpp[0]
        {
            float acc = wb;
            #pragma unroll
            for (int k = 0; k < 4; ++k) {
                acc = fmaf(tg0[k].x, wsl[k].x, acc);
                acc = fmaf(tg0[k].y, wsl[k].y, acc);
                acc = fmaf(tg0[k].z, wsl[k].z, acc);
                acc = fmaf(tg0[k].w, wsl[k].w, acc);
            }
            tpp[0][wv * 64 + lane] = acc;
        }
        bar();   // bfrag/wsl reads done before hisb[1] is reused (iter-0 conv)

        // (7) convert batch 0 -> hisb[0] (data-dep vmcnt waits, progressive)
        #pragma unroll
        for (int j = 0; j < 13; ++j) {
            int i = t + j * 512;
            if (i < 6400) {
                int s = i >> 5, d8 = i & 31;
                int pc = (d8 >> 1) ^ (s & 15);
                uint2 v;
                v.x = cvt_pk_bf16(x0[j].x, x0[j].y);
                v.y = cvt_pk_bf16(x0[j].z, x0[j].w);
                *(uint2*)((char*)hisb[0] + s * 256 + pc * 16 + (d8 & 1) * 8) = v;
            }
        }
        bar();   // hisb[0] + tpp[0] visible; batch-1 loads still in flight
    }

    // ================= main loop =================
    for (int n = 0; n < KB_; ++n) {
        const int b = b0 + n;
        const int p = n & 1;
        const unsigned short* hb = hisb[p];
        float mk2 = 0.f;

        // (1) tproj for this batch from LDS partials
        const float* tpc = tpp[p];
        float th[4];
        #pragma unroll
        for (int nt = 0; nt < 4; ++nt) {
            int h = nt * 16 + lm;
            float s0 = tpc[h] + tpc[64 + h] + tpc[128 + h] + tpc[192 + h];
            float s1 = tpc[256 + h] + tpc[320 + h] + tpc[384 + h] + tpc[448 + h];
            th[nt] = s0 + s1;
        }

        // (2) alpha via MFMA: 13 tiles over 8 waves
        #pragma unroll
        for (int tt = 0; tt < 2; ++tt) {
            int tile = wv + tt * 8;
            if (tile < 13) {
                int row0 = tile * 16;
                int ar = row0 + lm; if (ar > S_ - 1) ar = S_ - 1;   // clamp pad rows

                f32x4 acc[4];
                #pragma unroll
                for (int nt = 0; nt < 4; ++nt) acc[nt] = (f32x4){0.f, 0.f, 0.f, 0.f};
                #pragma unroll
                for (int kt = 0; kt < 4; ++kt) {
                    int c = (kt * 4 + q) ^ (ar & 15);
                    short8_t av = *(const short8_t*)((const char*)hb + ar * 256 + c * 16);
                    #pragma unroll
                    for (int nt = 0; nt < 4; ++nt)
                        acc[nt] = __builtin_amdgcn_mfma_f32_16x16x32_bf16(av, bfrag[kt * 4 + nt], acc[nt], 0, 0, 0);
                }
                // epilogue: +tproj, relu, dot O (O_bias softmax-invariant)
                float part[4];
                #pragma unroll
                for (int r = 0; r < 4; ++r) {
                    float sum = 0.f;
                    #pragma unroll
                    for (int nt = 0; nt < 4; ++nt) {
                        int h = nt * 16 + lm;
                        float v = acc[nt][r] + th[nt];
                        v = fmaxf(v, 0.f);
                        sum = fmaf(v, ov_s[h], sum);
                    }
                    part[r] = sum;
                }
                #pragma unroll
                for (int off = 1; off < 16; off <<= 1) {
                    #pragma unroll
                    for (int r = 0; r < 4; ++r)
                        part[r] += __shfl_xor(part[r], off);
                }
                if (lm == 0) {
                    #pragma unroll
                    for (int r = 0; r < 4; ++r)
                        alph[row0 + q * 4 + r] = part[r];
                }
            }
        }
        bar();   // A: alpha ready

        // (4) softmax over s = 0..199 (8 waves)
        float a = (t < S_) ? alph[t] - mk * MASK_SCALE : -INFINITY;
        float m = a;
        #pragma unroll
        for (int off = 1; off < 64; off <<= 1) m = fmaxf(m, __shfl_xor(m, off));
        if (lane == 0) red8[wv] = m;
        bar();   // B: per-wave maxima ready
        m = red8[0];
        #pragma unroll
        for (int k = 1; k < 8; ++k) m = fmaxf(m, red8[k]);
        float e = (t < S_) ? __expf(a - m) : 0.f;
        if (t < S_) attw[t] = e;
        float ssum = e;
        #pragma unroll
        for (int off = 1; off < 64; off <<= 1) ssum += __shfl_xor(ssum, off);
        if (lane == 0) red8b[wv] = ssum;
        bar();   // C: attw + per-wave sums ready
        float tot = red8b[0];
        #pragma unroll
        for (int k = 1; k < 8; ++k) tot += red8b[k];
        const float inv = 1.f / tot;

        // (5) pooling (current buffer)
        const int d8 = t & 31;           // 8B index: d = d8*4 .. d8*4+3
        const int sg = t >> 5;           // 0..15 s-groups
        float acc0 = 0.f, acc1 = 0.f, acc2 = 0.f, acc3 = 0.f;
        #pragma unroll 4
        for (int s = sg; s < S_; s += 16) {
            float w = attw[s];           // half-wave-uniform broadcast
            int pc = (d8 >> 1) ^ (s & 15);
            ushort4_t v = *(const ushort4_t*)((const char*)hb + s * 256 + pc * 16 + (d8 & 1) * 8);
            acc0 = fmaf(w, bf2f(v[0]), acc0);
            acc1 = fmaf(w, bf2f(v[1]), acc1);
            acc2 = fmaf(w, bf2f(v[2]), acc2);
            acc3 = fmaf(w, bf2f(v[3]), acc3);
        }
        acc0 += __shfl_xor(acc0, 32);
        acc1 += __shfl_xor(acc1, 32);
        acc2 += __shfl_xor(acc2, 32);
        acc3 += __shfl_xor(acc3, 32);
        if (wv && lane < 32) {
            float4 pr; pr.x = acc0; pr.y = acc1; pr.z = acc2; pr.w = acc3;
            *(float4*)(&pool_s[(wv - 1) * D_ + d8 * 4]) = pr;
        }

        // (6) tproj for batch n+1 (tg arrived ~1 iteration ago) -> tpp[p^1]
        if (n < KB_ - 1) {
            float acc = wb;
            #pragma unroll
            for (int k = 0; k < 4; ++k) {
                acc = fmaf(tg[k].x, wsl[k].x, acc);
                acc = fmaf(tg[k].y, wsl[k].y, acc);
                acc = fmaf(tg[k].z, wsl[k].z, acc);
                acc = fmaf(tg[k].w, wsl[k].w, acc);
            }
            tpp[p ^ 1][wv * 64 + lane] = acc;
        }

        // (7) convert batch n+1 -> other buffer (the vmcnt stall lives here)
        if (n < KB_ - 1) {
            unsigned short* hn = hisb[p ^ 1];
            #pragma unroll
            for (int j = 0; j < 13; ++j) {
                int i = t + j * 512;
                if (i < 6400) {
                    int s = i >> 5, d8c = i & 31;
                    int pc = (d8c >> 1) ^ (s & 15);
                    uint2 v;
                    v.x = cvt_pk_bf16(x[j].x, x[j].y);
                    v.y = cvt_pk_bf16(x[j].z, x[j].w);
                    *(uint2*)((char*)hn + s * 256 + pc * 16 + (d8c & 1) * 8) = v;
                }
            }
        }

        // (8) issue batch n+2 NOW (x regs just freed) -- before bar D, so HBM
        // never idles across the iteration boundary. tg/mask first.
        if (n < KB_ - 2) {
            const float4* tg4 = (const float4*)(target + (size_t)(b + 2) * D_) + wv * 4;
            #pragma unroll
            for (int k = 0; k < 4; ++k) tg[k] = tg4[k];
            if (t < S_) mk2 = mask[(size_t)(b + 2) * S_ + t];
            const float4* hb4n = (const float4*)(his + (size_t)(b + 2) * S_ * D_);
            #pragma unroll
            for (int j = 0; j < 13; ++j) {
                int i = t + j * 512;
                if (i < 6400) x[j] = hb4n[i];
            }
        }
        __builtin_amdgcn_sched_barrier(0);
        bar();   // D: pool partials + next buffer + next tpp ready

        // (10) final out write for batch n
        if (wv == 0 && lane < 32) {
            #pragma unroll
            for (int k = 0; k < 7; ++k) {
                const float4 pr = *(const float4*)(&pool_s[k * D_ + d8 * 4]);
                acc0 += pr.x; acc1 += pr.y; acc2 += pr.z; acc3 += pr.w;
            }
            float4 o;
            o.x = acc0 * inv; o.y = acc1 * inv; o.z = acc2 * inv; o.w = acc3 * inv;
            *(float4*)(out + (size_t)b * D_ + d8 * 4) = o;
        }

        mk = mkn;
        mkn = mk2;
    }
}

// ---------------------------------------------------------------------------
extern "C" void kernel_launch(void* const* d_in, const int* in_sizes, int n_in,
                              void* d_out, int out_size, void* d_ws, size_t ws_size,
                              hipStream_t stream) {
    const float* his    = (const float*)d_in[0];
    const float* target = (const float*)d_in[1];
    const float* mask   = (const float*)d_in[2];
    const float* W      = (const float*)d_in[3];
    const float* W_bias = (const float*)d_in[4];
    const float* Ovec   = (const float*)d_in[5];
    // O_bias (d_in[6]) is softmax-invariant -> unused
    float* out = (float*)d_out;

    fused_kernel<<<GRID_, 512, 0, stream>>>(his, mask, target, W, W_bias, Ovec, out);
}